// Round 4
// baseline (321.731 us; speedup 1.0000x reference)
//
#include <hip/hip_runtime.h>
#include <hip/hip_bf16.h>
#include <hip/hip_cooperative_groups.h>
#include <math.h>

namespace cg = cooperative_groups;

#define N_TOT 8192
#define HALF_N 4096
#define D_DIM 512
#define BM 128
#define BK 32
#define NTILES 2080   // 64*65/2 upper-triangle 128x128 tiles

typedef short bf16x8_t __attribute__((ext_vector_type(8)));
typedef float f32x4_t __attribute__((ext_vector_type(4)));

typedef __attribute__((address_space(1))) unsigned int g_u32;
typedef __attribute__((address_space(3))) unsigned int l_u32;

__device__ __forceinline__ unsigned short f2bf(float x) {
    union { float f; unsigned int u; } v; v.f = x;
    unsigned int r = v.u + 0x7FFFu + ((v.u >> 16) & 1u);
    return (unsigned short)(r >> 16);
}

// ---------------------------------------------------------------------------
// Shared device helpers (used by both fused and fallback paths)
// ---------------------------------------------------------------------------
__device__ __forceinline__ void normalize_row(
    const float* __restrict__ p1, const float* __restrict__ p2,
    unsigned short* __restrict__ zbf, int row, int lane)
{
    const float* src = (row < HALF_N) ? p1 + (size_t)row * D_DIM
                                      : p2 + (size_t)(row - HALF_N) * D_DIM;
    float4 a = *(const float4*)(src + lane * 4);
    float4 b = *(const float4*)(src + 256 + lane * 4);
    float s = a.x*a.x + a.y*a.y + a.z*a.z + a.w*a.w
            + b.x*b.x + b.y*b.y + b.z*b.z + b.w*b.w;
    #pragma unroll
    for (int m = 1; m < 64; m <<= 1) s += __shfl_xor(s, m, 64);
    float inv = 1.0f / fmaxf(sqrtf(s), 1e-8f);
    ushort4 oa, ob;
    oa.x = f2bf(a.x * inv); oa.y = f2bf(a.y * inv);
    oa.z = f2bf(a.z * inv); oa.w = f2bf(a.w * inv);
    ob.x = f2bf(b.x * inv); ob.y = f2bf(b.y * inv);
    ob.z = f2bf(b.z * inv); ob.w = f2bf(b.w * inv);
    unsigned short* dst = zbf + (size_t)row * D_DIM;
    *(ushort4*)(dst + lane * 4) = oa;
    *(ushort4*)(dst + 256 + lane * 4) = ob;
}

// One 128x128 upper-triangle tile: MFMA + fused exp/rowsum/colsum/pos epilogue.
// As/Bs: BM*BK bf16, 16B-aligned.
__device__ __forceinline__ void do_tile(
    const unsigned short* __restrict__ zbf, float* __restrict__ rowsum,
    float* __restrict__ pos, unsigned short* As, unsigned short* Bs,
    int t, int tid)
{
    const int lane = tid & 63;
    const int w = tid >> 6;
    const int wr = w >> 1, wc = w & 1;
    const int q = lane >> 4, l15 = lane & 15;

    int bi = (int)((sqrtf(8.0f * (float)t + 1.0f) - 1.0f) * 0.5f);
    while ((bi + 1) * (bi + 2) / 2 <= t) ++bi;
    while (bi * (bi + 1) / 2 > t) --bi;
    const int bx = bi;                       // col tile (larger)
    const int by = t - bi * (bi + 1) / 2;    // row tile
    const bool isDiag = (bx == by);
    const bool hasPos = (bx - by == 32);
    const int rowBase = by * BM;
    const int colBase = bx * BM;

    // staging: chunk = 8 bf16 = 16B; dest chunk index = tid and 256+tid
    const int ci0 = tid;
    const int ci1 = 256 + tid;
    const int r0 = ci0 >> 2, cc0 = ci0 & 3;
    const int r1 = ci1 >> 2, cc1 = ci1 & 3;
    const int gc0 = cc0 ^ ((r0 >> 1) & 3);  // XOR source swizzle (0 conflicts)
    const int gc1 = cc1 ^ ((r1 >> 1) & 3);

    f32x4_t acc[4][4] = {};

    for (int kb = 0; kb < D_DIM; kb += BK) {
        const unsigned short* ga0 = zbf + (size_t)(rowBase + r0) * D_DIM + kb + gc0 * 8;
        const unsigned short* ga1 = zbf + (size_t)(rowBase + r1) * D_DIM + kb + gc1 * 8;
        const unsigned short* gb0 = zbf + (size_t)(colBase + r0) * D_DIM + kb + gc0 * 8;
        const unsigned short* gb1 = zbf + (size_t)(colBase + r1) * D_DIM + kb + gc1 * 8;
        __builtin_amdgcn_global_load_lds((const g_u32*)ga0, (l_u32*)&As[ci0 * 8], 16, 0, 0);
        __builtin_amdgcn_global_load_lds((const g_u32*)ga1, (l_u32*)&As[ci1 * 8], 16, 0, 0);
        __builtin_amdgcn_global_load_lds((const g_u32*)gb0, (l_u32*)&Bs[ci0 * 8], 16, 0, 0);
        __builtin_amdgcn_global_load_lds((const g_u32*)gb1, (l_u32*)&Bs[ci1 * 8], 16, 0, 0);
        __syncthreads();

        bf16x8_t af[4], bfr[4];
        #pragma unroll
        for (int i = 0; i < 4; i++) {
            const int ra = wr * 64 + i * 16 + l15;
            const int rb = wc * 64 + i * 16 + l15;
            af[i]  = *(const bf16x8_t*)&As[ra * BK + (q ^ ((ra >> 1) & 3)) * 8];
            bfr[i] = *(const bf16x8_t*)&Bs[rb * BK + (q ^ ((rb >> 1) & 3)) * 8];
        }
        #pragma unroll
        for (int i = 0; i < 4; i++)
            #pragma unroll
            for (int j = 0; j < 4; j++)
                acc[i][j] = __builtin_amdgcn_mfma_f32_16x16x32_bf16(af[i], bfr[j], acc[i][j], 0, 0, 0);
        __syncthreads();
    }

    // Epilogue. C/D layout (16x16x32): col = lane&15, row = (lane>>4)*4 + reg.
    float colacc[4] = {0.f, 0.f, 0.f, 0.f};
    #pragma unroll
    for (int i = 0; i < 4; i++) {
        #pragma unroll
        for (int r = 0; r < 4; r++) {
            const int row = rowBase + wr * 64 + i * 16 + q * 4 + r;
            float rs = 0.0f;
            #pragma unroll
            for (int j = 0; j < 4; j++) {
                const int col = colBase + wc * 64 + j * 16 + l15;
                const float c = acc[i][j][r];
                float e = __expf(c);
                if (isDiag && col == row) e = 0.0f;
                rs += e;
                colacc[j] += e;
                if (hasPos && col == row + HALF_N) { pos[row] = c; pos[col] = c; }
            }
            rs += __shfl_xor(rs, 1); rs += __shfl_xor(rs, 2);
            rs += __shfl_xor(rs, 4); rs += __shfl_xor(rs, 8);
            if (l15 == 0) atomicAdd(&rowsum[row], rs);
        }
    }
    if (!isDiag) {
        #pragma unroll
        for (int j = 0; j < 4; j++) {
            float cs = colacc[j];
            cs += __shfl_xor(cs, 16);
            cs += __shfl_xor(cs, 32);
            if (q == 0) atomicAdd(&rowsum[colBase + wc * 64 + j * 16 + l15], cs);
        }
    }
}

// ---------------------------------------------------------------------------
// Fused persistent cooperative kernel (grid sized by occupancy query).
// ---------------------------------------------------------------------------
__global__ __launch_bounds__(256) void k_fused(
    const float* __restrict__ p1, const float* __restrict__ p2,
    unsigned short* __restrict__ zbf, float* __restrict__ rowsum,
    float* __restrict__ pos, float* __restrict__ out)
{
    __shared__ __align__(16) unsigned short As[BM * BK];
    __shared__ __align__(16) unsigned short Bs[BM * BK];

    const int tid = threadIdx.x;
    const int bid = blockIdx.x;
    const int G = gridDim.x;
    const int lane = tid & 63;
    const int w = tid >> 6;

    // Phase 1: normalize + zero accumulators (grid-stride)
    for (int g = bid * 256 + tid; g < N_TOT; g += G * 256) rowsum[g] = 0.0f;
    if (bid == 0 && tid == 0) out[0] = 0.0f;
    for (int row = bid * 4 + w; row < N_TOT; row += G * 4)
        normalize_row(p1, p2, zbf, row, lane);

    __threadfence();
    cg::this_grid().sync();
    __threadfence();

    // Phase 2: triangular GEMM (grid-stride over tiles)
    for (int t = bid; t < NTILES; t += G)
        do_tile(zbf, rowsum, pos, As, Bs, t, tid);

    __threadfence();
    cg::this_grid().sync();
    __threadfence();

    // Phase 3: finalize (grid-stride)
    {
        float s = 0.0f;
        for (int g = bid * 256 + tid; g < N_TOT; g += G * 256)
            s += logf(rowsum[g]) - pos[g];
        #pragma unroll
        for (int m = 1; m < 64; m <<= 1) s += __shfl_xor(s, m, 64);
        float* red = (float*)As;  // safe: after grid sync / barriers below
        __syncthreads();
        if ((tid & 63) == 0) red[tid >> 6] = s;
        __syncthreads();
        if (tid == 0) {
            float tot = red[0] + red[1] + red[2] + red[3];
            if (tot != 0.0f) atomicAdd(out, tot * (1.0f / (float)N_TOT));
        }
    }
}

// ---------------------------------------------------------------------------
// Fallback path (proven R2 kernels) in case cooperative launch fails.
// ---------------------------------------------------------------------------
__global__ __launch_bounds__(256) void k_normalize(
    const float* __restrict__ p1, const float* __restrict__ p2,
    unsigned short* __restrict__ zbf, float* __restrict__ rowsum,
    float* __restrict__ out)
{
    if (threadIdx.x < 4) rowsum[blockIdx.x * 4 + threadIdx.x] = 0.0f;
    if (blockIdx.x == 0 && threadIdx.x == 0) out[0] = 0.0f;
    normalize_row(p1, p2, zbf, blockIdx.x * 4 + (threadIdx.x >> 6), threadIdx.x & 63);
}

__global__ __launch_bounds__(256) void k_gemm(
    const unsigned short* __restrict__ zbf,
    float* __restrict__ rowsum, float* __restrict__ pos)
{
    __shared__ __align__(16) unsigned short As[BM * BK];
    __shared__ __align__(16) unsigned short Bs[BM * BK];
    do_tile(zbf, rowsum, pos, As, Bs, blockIdx.x, threadIdx.x);
}

__global__ __launch_bounds__(256) void k_finalize(
    const float* __restrict__ rowsum, const float* __restrict__ pos,
    float* __restrict__ out)
{
    const int t = threadIdx.x;
    const int i = blockIdx.x * 256 + t;
    float s = logf(rowsum[i]) - pos[i];
    #pragma unroll
    for (int m = 1; m < 64; m <<= 1) s += __shfl_xor(s, m, 64);
    __shared__ float red[4];
    if ((t & 63) == 0) red[t >> 6] = s;
    __syncthreads();
    if (t == 0)
        atomicAdd(out, (red[0] + red[1] + red[2] + red[3]) * (1.0f / (float)N_TOT));
}

extern "C" void kernel_launch(void* const* d_in, const int* in_sizes, int n_in,
                              void* d_out, int out_size, void* d_ws, size_t ws_size,
                              hipStream_t stream) {
    const float* p1 = (const float*)d_in[0];
    const float* p2 = (const float*)d_in[1];

    unsigned short* zbf = (unsigned short*)d_ws;                       // 8 MB
    float* rowsum = (float*)((char*)d_ws + (size_t)N_TOT * D_DIM * 2); // 32 KB
    float* pos    = rowsum + N_TOT;                                    // 32 KB
    float* outp   = (float*)d_out;

    // Size cooperative grid from the real occupancy (AGPR-aware).
    int maxPerCU = 0;
    hipError_t oe = hipOccupancyMaxActiveBlocksPerMultiprocessor(
        &maxPerCU, (const void*)k_fused, 256, 0);
    int grid = NTILES;
    if (oe == hipSuccess && maxPerCU > 0) {
        long cap = (long)maxPerCU * 256;  // 256 CUs on MI355X
        if (cap < grid) grid = (int)cap;
    } else {
        grid = 512;  // conservative
    }

    void* args[] = {(void*)&p1, (void*)&p2, (void*)&zbf,
                    (void*)&rowsum, (void*)&pos, (void*)&outp};
    hipError_t le = hipLaunchCooperativeKernel((const void*)k_fused, dim3(grid),
                                               dim3(256), args, 0, stream);
    if (le != hipSuccess) {
        // Fallback: proven three-kernel path (R2, 146.8 us).
        k_normalize<<<N_TOT / 4, 256, 0, stream>>>(p1, p2, zbf, rowsum, outp);
        k_gemm<<<NTILES, 256, 0, stream>>>(zbf, rowsum, pos);
        k_finalize<<<N_TOT / 256, 256, 0, stream>>>(rowsum, pos, outp);
    }
}

// Round 5
// 252.715 us; speedup vs baseline: 1.2731x; 1.2731x over previous
//
#include <hip/hip_runtime.h>
#include <hip/hip_bf16.h>
#include <math.h>

#define N_TOT 8192
#define HALF_N 4096
#define D_DIM 512
#define BM 128
#define BKF 128        // K-chunk (fp8): 4 iterations over D=512
#define NTILES 2080    // 64*65/2 upper-triangle 128x128 tiles

typedef int i32x4 __attribute__((ext_vector_type(4)));
typedef int i32x8 __attribute__((ext_vector_type(8)));
typedef float f32x4_t __attribute__((ext_vector_type(4)));

typedef __attribute__((address_space(1))) unsigned int g_u32;
typedef __attribute__((address_space(3))) unsigned int l_u32;

// Kernel 1: L2-normalize rows of [p1;p2] -> fp8 e4m3 Z; zero rowsum + counter.
__global__ __launch_bounds__(256) void k_normalize(
    const float* __restrict__ p1, const float* __restrict__ p2,
    unsigned char* __restrict__ zf8, float* __restrict__ rowsum,
    unsigned int* __restrict__ counter)
{
    const int w = threadIdx.x >> 6;
    const int lane = threadIdx.x & 63;
    const int row = blockIdx.x * 4 + w;

    if (threadIdx.x < 4) rowsum[blockIdx.x * 4 + threadIdx.x] = 0.0f;
    if (blockIdx.x == 0 && threadIdx.x == 0) *counter = 0u;

    const float* src = (row < HALF_N) ? p1 + (size_t)row * D_DIM
                                      : p2 + (size_t)(row - HALF_N) * D_DIM;
    float4 a = *(const float4*)(src + lane * 4);
    float4 b = *(const float4*)(src + 256 + lane * 4);
    float s = a.x*a.x + a.y*a.y + a.z*a.z + a.w*a.w
            + b.x*b.x + b.y*b.y + b.z*b.z + b.w*b.w;
    #pragma unroll
    for (int m = 1; m < 64; m <<= 1) s += __shfl_xor(s, m, 64);
    float inv = 1.0f / fmaxf(sqrtf(s), 1e-8f);

    // pack 4 floats -> 4 fp8 e4m3 (OCP on gfx950) per int, RNE
    int pk0 = __builtin_amdgcn_cvt_pk_fp8_f32(a.x * inv, a.y * inv, 0, false);
    pk0     = __builtin_amdgcn_cvt_pk_fp8_f32(a.z * inv, a.w * inv, pk0, true);
    int pk1 = __builtin_amdgcn_cvt_pk_fp8_f32(b.x * inv, b.y * inv, 0, false);
    pk1     = __builtin_amdgcn_cvt_pk_fp8_f32(b.z * inv, b.w * inv, pk1, true);

    unsigned char* dst = zf8 + (size_t)row * D_DIM;
    *(int*)(dst + lane * 4) = pk0;
    *(int*)(dst + 256 + lane * 4) = pk1;
}

// Kernel 2: upper-triangle tiles of sim = Z*Z^T via MX-fp8 MFMA 16x16x128
// (scales = 1.0). Fused exp + row/col sums (symmetry) + pos extraction.
// Last finishing block (device counter) computes the final mean.
__global__ __launch_bounds__(256) void k_gemm(
    const unsigned char* __restrict__ zf8,
    float* __restrict__ rowsum, float* __restrict__ pos,
    unsigned int* __restrict__ counter, float* __restrict__ out)
{
    __shared__ __align__(16) unsigned char As[BM * BKF];  // 16 KB
    __shared__ __align__(16) unsigned char Bs[BM * BKF];  // 16 KB

    const int tid = threadIdx.x;
    const int lane = tid & 63;
    const int w = tid >> 6;
    const int wr = w >> 1, wc = w & 1;
    const int q = lane >> 4, l15 = lane & 15;

    // triangular block mapping: t -> (bx >= by)
    const int t = blockIdx.x;
    int bi = (int)((sqrtf(8.0f * (float)t + 1.0f) - 1.0f) * 0.5f);
    while ((bi + 1) * (bi + 2) / 2 <= t) ++bi;
    while (bi * (bi + 1) / 2 > t) --bi;
    const int bx = bi;                       // col tile (larger)
    const int by = t - bi * (bi + 1) / 2;    // row tile
    const bool isDiag = (bx == by);
    const bool hasPos = (bx - by == 32);
    const int rowBase = by * BM;
    const int colBase = bx * BM;

    f32x4_t acc[4][4] = {};

    for (int kb = 0; kb < D_DIM; kb += BKF) {
        // stage A/B 128x128B panels; 16B chunks, XOR source-swizzle so
        // fragment ds_read_b128 is conflict-free while dests stay
        // lane-contiguous (global_load_lds requirement).
        #pragma unroll
        for (int s2 = 0; s2 < 4; s2++) {
            const int ci = tid + 256 * s2;
            const int row = ci >> 3, cc = ci & 7;
            const int gc = cc ^ (row & 7);
            const unsigned char* ga = zf8 + (size_t)(rowBase + row) * D_DIM + kb + gc * 16;
            const unsigned char* gb = zf8 + (size_t)(colBase + row) * D_DIM + kb + gc * 16;
            __builtin_amdgcn_global_load_lds((const g_u32*)ga, (l_u32*)&As[ci * 16], 16, 0, 0);
            __builtin_amdgcn_global_load_lds((const g_u32*)gb, (l_u32*)&Bs[ci * 16], 16, 0, 0);
        }
        __syncthreads();

        // B fragments: lane holds B[n = l15][k = q*32 .. q*32+31]
        i32x8 bfr[4];
        #pragma unroll
        for (int j = 0; j < 4; j++) {
            const int rb = wc * 64 + j * 16 + l15;
            i32x4 lo = *(const i32x4*)&Bs[rb * BKF + ((2 * q) ^ (rb & 7)) * 16];
            i32x4 hi = *(const i32x4*)&Bs[rb * BKF + ((2 * q + 1) ^ (rb & 7)) * 16];
            i32x8 v; v[0]=lo[0]; v[1]=lo[1]; v[2]=lo[2]; v[3]=lo[3];
                     v[4]=hi[0]; v[5]=hi[1]; v[6]=hi[2]; v[7]=hi[3];
            bfr[j] = v;
        }
        #pragma unroll
        for (int i = 0; i < 4; i++) {
            const int ra = wr * 64 + i * 16 + l15;
            i32x4 lo = *(const i32x4*)&As[ra * BKF + ((2 * q) ^ (ra & 7)) * 16];
            i32x4 hi = *(const i32x4*)&As[ra * BKF + ((2 * q + 1) ^ (ra & 7)) * 16];
            i32x8 av; av[0]=lo[0]; av[1]=lo[1]; av[2]=lo[2]; av[3]=lo[3];
                      av[4]=hi[0]; av[5]=hi[1]; av[6]=hi[2]; av[7]=hi[3];
            #pragma unroll
            for (int j = 0; j < 4; j++)
                acc[i][j] = __builtin_amdgcn_mfma_scale_f32_16x16x128_f8f6f4(
                    av, bfr[j], acc[i][j], 0, 0, 0, 127, 0, 127);
        }
        __syncthreads();
    }

    // Epilogue. C/D layout (16x16 family): col = lane&15, row = (lane>>4)*4 + reg.
    float colacc[4] = {0.f, 0.f, 0.f, 0.f};
    #pragma unroll
    for (int i = 0; i < 4; i++) {
        #pragma unroll
        for (int r = 0; r < 4; r++) {
            const int row = rowBase + wr * 64 + i * 16 + q * 4 + r;
            float rs = 0.0f;
            #pragma unroll
            for (int j = 0; j < 4; j++) {
                const int col = colBase + wc * 64 + j * 16 + l15;
                const float c = acc[i][j][r];
                float e = __expf(c);
                if (isDiag && col == row) e = 0.0f;
                rs += e;
                colacc[j] += e;
                if (hasPos && col == row + HALF_N) { pos[row] = c; pos[col] = c; }
            }
            rs += __shfl_xor(rs, 1); rs += __shfl_xor(rs, 2);
            rs += __shfl_xor(rs, 4); rs += __shfl_xor(rs, 8);
            if (l15 == 0) atomicAdd(&rowsum[row], rs);
        }
    }
    if (!isDiag) {
        #pragma unroll
        for (int j = 0; j < 4; j++) {
            float cs = colacc[j];
            cs += __shfl_xor(cs, 16);
            cs += __shfl_xor(cs, 32);
            if (q == 0) atomicAdd(&rowsum[colBase + wc * 64 + j * 16 + l15], cs);
        }
    }

    // Last-block-done finalize: mean(log(rowsum) - pos) -> out.
    __shared__ bool sLast;
    __threadfence();   // release: flush pos stores / make atomics visible
    __syncthreads();
    if (tid == 0) sLast = (atomicAdd(counter, 1u) == NTILES - 1);
    __syncthreads();
    if (sLast) {
        __threadfence();  // acquire: invalidate so we see all blocks' writes
        float s = 0.0f;
        for (int g = tid; g < N_TOT; g += 256) s += logf(rowsum[g]) - pos[g];
        #pragma unroll
        for (int m = 1; m < 64; m <<= 1) s += __shfl_xor(s, m, 64);
        __shared__ float red[4];
        if ((tid & 63) == 0) red[tid >> 6] = s;
        __syncthreads();
        if (tid == 0)
            out[0] = (red[0] + red[1] + red[2] + red[3]) * (1.0f / (float)N_TOT);
    }
}

extern "C" void kernel_launch(void* const* d_in, const int* in_sizes, int n_in,
                              void* d_out, int out_size, void* d_ws, size_t ws_size,
                              hipStream_t stream) {
    const float* p1 = (const float*)d_in[0];
    const float* p2 = (const float*)d_in[1];

    unsigned char* zf8 = (unsigned char*)d_ws;                          // 4 MB
    float* rowsum = (float*)((char*)d_ws + (size_t)N_TOT * D_DIM);      // 32 KB
    float* pos    = rowsum + N_TOT;                                     // 32 KB
    unsigned int* counter = (unsigned int*)(pos + N_TOT);               // 4 B
    float* outp   = (float*)d_out;

    k_normalize<<<N_TOT / 4, 256, 0, stream>>>(p1, p2, zf8, rowsum, counter);
    k_gemm<<<NTILES, 256, 0, stream>>>(zf8, rowsum, pos, counter, outp);
}

// Round 6
// 244.876 us; speedup vs baseline: 1.3138x; 1.0320x over previous
//
#include <hip/hip_runtime.h>
#include <hip/hip_bf16.h>
#include <math.h>

#define N_TOT 8192
#define HALF_N 4096
#define D_DIM 512
#define BM 128
#define BK 32          // fp8 bytes per row-chunk; 16 K-iterations
#define NTILES 2080    // 64*65/2 upper-triangle 128x128 tiles

typedef float f32x4_t __attribute__((ext_vector_type(4)));

typedef __attribute__((address_space(1))) unsigned int g_u32;
typedef __attribute__((address_space(3))) unsigned int l_u32;

// Kernel 1: L2-normalize rows of [p1;p2] -> fp8 e4m3 Z; zero rowsum + counter.
__global__ __launch_bounds__(256) void k_normalize(
    const float* __restrict__ p1, const float* __restrict__ p2,
    unsigned char* __restrict__ zf8, float* __restrict__ rowsum,
    unsigned int* __restrict__ counter)
{
    const int w = threadIdx.x >> 6;
    const int lane = threadIdx.x & 63;
    const int row = blockIdx.x * 4 + w;

    if (threadIdx.x < 4) rowsum[blockIdx.x * 4 + threadIdx.x] = 0.0f;
    if (blockIdx.x == 0 && threadIdx.x == 0) *counter = 0u;

    const float* src = (row < HALF_N) ? p1 + (size_t)row * D_DIM
                                      : p2 + (size_t)(row - HALF_N) * D_DIM;
    float4 a = *(const float4*)(src + lane * 4);
    float4 b = *(const float4*)(src + 256 + lane * 4);
    float s = a.x*a.x + a.y*a.y + a.z*a.z + a.w*a.w
            + b.x*b.x + b.y*b.y + b.z*b.z + b.w*b.w;
    #pragma unroll
    for (int m = 1; m < 64; m <<= 1) s += __shfl_xor(s, m, 64);
    float inv = 1.0f / fmaxf(sqrtf(s), 1e-8f);

    // pack 4 floats -> 4 fp8 e4m3 (OCP) per int, RNE (validated R5)
    int pk0 = __builtin_amdgcn_cvt_pk_fp8_f32(a.x * inv, a.y * inv, 0, false);
    pk0     = __builtin_amdgcn_cvt_pk_fp8_f32(a.z * inv, a.w * inv, pk0, true);
    int pk1 = __builtin_amdgcn_cvt_pk_fp8_f32(b.x * inv, b.y * inv, 0, false);
    pk1     = __builtin_amdgcn_cvt_pk_fp8_f32(b.z * inv, b.w * inv, pk1, true);

    unsigned char* dst = zf8 + (size_t)row * D_DIM;
    *(int*)(dst + lane * 4) = pk0;
    *(int*)(dst + 256 + lane * 4) = pk1;
}

// Kernel 2: upper-triangle tiles of sim = Z*Z^T via non-scaled fp8 MFMA
// 16x16x32 (bf16 rate, half the staging bytes; Z = 4 MB fits per-XCD L2).
// R2-proven loop structure: BK=32, 16 iters, 2 global_load_lds/thread/iter.
// Fused exp + row/col sums (symmetry) + pos; last-done block finalizes.
__global__ __launch_bounds__(256) void k_gemm(
    const unsigned char* __restrict__ zf8,
    float* __restrict__ rowsum, float* __restrict__ pos,
    unsigned int* __restrict__ counter, float* __restrict__ out)
{
    __shared__ __align__(16) unsigned char As[BM * BK];  // 4 KB
    __shared__ __align__(16) unsigned char Bs[BM * BK];  // 4 KB

    const int tid = threadIdx.x;
    const int lane = tid & 63;
    const int w = tid >> 6;
    const int wr = w >> 1, wc = w & 1;
    const int q = lane >> 4, l15 = lane & 15;

    // triangular block mapping: t -> (bx >= by)
    const int t = blockIdx.x;
    int bi = (int)((sqrtf(8.0f * (float)t + 1.0f) - 1.0f) * 0.5f);
    while ((bi + 1) * (bi + 2) / 2 <= t) ++bi;
    while (bi * (bi + 1) / 2 > t) --bi;
    const int bx = bi;                       // col tile (larger)
    const int by = t - bi * (bi + 1) / 2;    // row tile
    const bool isDiag = (bx == by);
    const bool hasPos = (bx - by == 32);
    const int rowBase = by * BM;
    const int colBase = bx * BM;

    // staging: 16B chunk per thread per array; row = tid>>1, half = tid&1
    const int srow = tid >> 1;
    const int soff = (tid & 1) * 16;

    f32x4_t acc[4][4] = {};

    for (int kb = 0; kb < D_DIM; kb += BK) {
        const unsigned char* ga = zf8 + (size_t)(rowBase + srow) * D_DIM + kb + soff;
        const unsigned char* gb = zf8 + (size_t)(colBase + srow) * D_DIM + kb + soff;
        __builtin_amdgcn_global_load_lds((const g_u32*)ga, (l_u32*)&As[tid * 16], 16, 0, 0);
        __builtin_amdgcn_global_load_lds((const g_u32*)gb, (l_u32*)&Bs[tid * 16], 16, 0, 0);
        __syncthreads();

        // fragments: lane (q,l15) holds 8 fp8 of row, k = q*8..q*8+7 (i64 op)
        long long bfr[4];
        #pragma unroll
        for (int j = 0; j < 4; j++)
            bfr[j] = *(const long long*)&Bs[(wc * 64 + j * 16 + l15) * BK + q * 8];
        #pragma unroll
        for (int i = 0; i < 4; i++) {
            const long long av = *(const long long*)&As[(wr * 64 + i * 16 + l15) * BK + q * 8];
            #pragma unroll
            for (int j = 0; j < 4; j++)
                acc[i][j] = __builtin_amdgcn_mfma_f32_16x16x32_fp8_fp8(av, bfr[j], acc[i][j], 0, 0, 0);
        }
        __syncthreads();
    }

    // Epilogue. C/D layout (16x16 family): col = lane&15, row = (lane>>4)*4 + reg.
    float colacc[4] = {0.f, 0.f, 0.f, 0.f};
    #pragma unroll
    for (int i = 0; i < 4; i++) {
        #pragma unroll
        for (int r = 0; r < 4; r++) {
            const int row = rowBase + wr * 64 + i * 16 + q * 4 + r;
            float rs = 0.0f;
            #pragma unroll
            for (int j = 0; j < 4; j++) {
                const int col = colBase + wc * 64 + j * 16 + l15;
                const float c = acc[i][j][r];
                float e = __expf(c);
                if (isDiag && col == row) e = 0.0f;
                rs += e;
                colacc[j] += e;
                if (hasPos && col == row + HALF_N) { pos[row] = c; pos[col] = c; }
            }
            rs += __shfl_xor(rs, 1); rs += __shfl_xor(rs, 2);
            rs += __shfl_xor(rs, 4); rs += __shfl_xor(rs, 8);
            if (l15 == 0) atomicAdd(&rowsum[row], rs);
        }
    }
    if (!isDiag) {
        #pragma unroll
        for (int j = 0; j < 4; j++) {
            float cs = colacc[j];
            cs += __shfl_xor(cs, 16);
            cs += __shfl_xor(cs, 32);
            if (q == 0) atomicAdd(&rowsum[colBase + wc * 64 + j * 16 + l15], cs);
        }
    }

    // Last-block-done finalize: mean(log(rowsum) - pos) -> out (validated R5).
    __shared__ bool sLast;
    __threadfence();   // release: flush pos stores before signaling
    __syncthreads();
    if (tid == 0) sLast = (atomicAdd(counter, 1u) == NTILES - 1);
    __syncthreads();
    if (sLast) {
        __threadfence();  // acquire: see all blocks' rowsum/pos
        float s = 0.0f;
        for (int g = tid; g < N_TOT; g += 256) s += logf(rowsum[g]) - pos[g];
        #pragma unroll
        for (int m = 1; m < 64; m <<= 1) s += __shfl_xor(s, m, 64);
        __shared__ float red[4];
        if ((tid & 63) == 0) red[tid >> 6] = s;
        __syncthreads();
        if (tid == 0)
            out[0] = (red[0] + red[1] + red[2] + red[3]) * (1.0f / (float)N_TOT);
    }
}

extern "C" void kernel_launch(void* const* d_in, const int* in_sizes, int n_in,
                              void* d_out, int out_size, void* d_ws, size_t ws_size,
                              hipStream_t stream) {
    const float* p1 = (const float*)d_in[0];
    const float* p2 = (const float*)d_in[1];

    unsigned char* zf8 = (unsigned char*)d_ws;                          // 4 MB
    float* rowsum = (float*)((char*)d_ws + (size_t)N_TOT * D_DIM);      // 32 KB
    float* pos    = rowsum + N_TOT;                                     // 32 KB
    unsigned int* counter = (unsigned int*)(pos + N_TOT);               // 4 B
    float* outp   = (float*)d_out;

    k_normalize<<<N_TOT / 4, 256, 0, stream>>>(p1, p2, zf8, rowsum, counter);
    k_gemm<<<NTILES, 256, 0, stream>>>(zf8, rowsum, pos, counter, outp);
}

// Round 7
// 109.250 us; speedup vs baseline: 2.9449x; 2.2414x over previous
//
#include <hip/hip_runtime.h>
#include <hip/hip_bf16.h>
#include <math.h>

#define N_TOT 8192
#define HALF_N 4096
#define D_DIM 512
#define BM 128
#define BK 64          // fp8 bytes per row-chunk; 8 K-iterations, 64B LDS rows
#define NTILES 2080    // 64*65/2 upper-triangle 128x128 tiles

typedef float f32x4_t __attribute__((ext_vector_type(4)));

typedef __attribute__((address_space(1))) unsigned int g_u32;
typedef __attribute__((address_space(3))) unsigned int l_u32;

// Kernel 1: L2-normalize rows of [p1;p2] -> fp8 e4m3 Z; zero rowsum + out.
__global__ __launch_bounds__(256) void k_normalize(
    const float* __restrict__ p1, const float* __restrict__ p2,
    unsigned char* __restrict__ zf8, float* __restrict__ rowsum,
    float* __restrict__ out)
{
    const int w = threadIdx.x >> 6;
    const int lane = threadIdx.x & 63;
    const int row = blockIdx.x * 4 + w;

    if (threadIdx.x < 4) rowsum[blockIdx.x * 4 + threadIdx.x] = 0.0f;
    if (blockIdx.x == 0 && threadIdx.x == 0) out[0] = 0.0f;

    const float* src = (row < HALF_N) ? p1 + (size_t)row * D_DIM
                                      : p2 + (size_t)(row - HALF_N) * D_DIM;
    float4 a = *(const float4*)(src + lane * 4);
    float4 b = *(const float4*)(src + 256 + lane * 4);
    float s = a.x*a.x + a.y*a.y + a.z*a.z + a.w*a.w
            + b.x*b.x + b.y*b.y + b.z*b.z + b.w*b.w;
    #pragma unroll
    for (int m = 1; m < 64; m <<= 1) s += __shfl_xor(s, m, 64);
    float inv = 1.0f / fmaxf(sqrtf(s), 1e-8f);

    // pack 4 floats -> 4 fp8 e4m3 (OCP) per int, RNE (validated R5/R6)
    int pk0 = __builtin_amdgcn_cvt_pk_fp8_f32(a.x * inv, a.y * inv, 0, false);
    pk0     = __builtin_amdgcn_cvt_pk_fp8_f32(a.z * inv, a.w * inv, pk0, true);
    int pk1 = __builtin_amdgcn_cvt_pk_fp8_f32(b.x * inv, b.y * inv, 0, false);
    pk1     = __builtin_amdgcn_cvt_pk_fp8_f32(b.z * inv, b.w * inv, pk1, true);

    unsigned char* dst = zf8 + (size_t)row * D_DIM;
    *(int*)(dst + lane * 4) = pk0;
    *(int*)(dst + 256 + lane * 4) = pk1;
}

// Kernel 2: upper-triangle tiles of sim = Z*Z^T via non-scaled fp8 MFMA
// 16x16x32 (bf16 rate). BK=64 bytes -> 64B LDS rows, R2's proven XOR
// chunk swizzle (gc = c ^ ((row>>1)&3)) => conflict-free-ish fragment reads,
// 8 barrier drains instead of 16. Z = 4MB, fits per-XCD L2.
// NO __threadfence anywhere (R5/R6 regression: device fence => L2 inval).
__global__ __launch_bounds__(256) void k_gemm(
    const unsigned char* __restrict__ zf8,
    float* __restrict__ rowsum, float* __restrict__ pos)
{
    __shared__ __align__(16) unsigned char As[BM * BK];  // 8 KB
    __shared__ __align__(16) unsigned char Bs[BM * BK];  // 8 KB

    const int tid = threadIdx.x;
    const int lane = tid & 63;
    const int w = tid >> 6;
    const int wr = w >> 1, wc = w & 1;
    const int q = lane >> 4, l15 = lane & 15;

    // triangular block mapping: t -> (bx >= by)
    const int t = blockIdx.x;
    int bi = (int)((sqrtf(8.0f * (float)t + 1.0f) - 1.0f) * 0.5f);
    while ((bi + 1) * (bi + 2) / 2 <= t) ++bi;
    while (bi * (bi + 1) / 2 > t) --bi;
    const int bx = bi;                       // col tile (larger)
    const int by = t - bi * (bi + 1) / 2;    // row tile
    const bool isDiag = (bx == by);
    const bool hasPos = (bx - by == 32);
    const int rowBase = by * BM;
    const int colBase = bx * BM;

    // staging: 16B chunks; dest chunk index = tid and 256+tid (lane-contig).
    // row = ci>>2 (64B rows), cc = ci&3, source chunk XOR-swizzled.
    const int ci0 = tid;
    const int ci1 = 256 + tid;
    const int r0 = ci0 >> 2, cc0 = ci0 & 3;
    const int r1 = ci1 >> 2, cc1 = ci1 & 3;
    const int gc0 = cc0 ^ ((r0 >> 1) & 3);
    const int gc1 = cc1 ^ ((r1 >> 1) & 3);

    f32x4_t acc[4][4] = {};

    for (int kb = 0; kb < D_DIM; kb += BK) {
        const unsigned char* ga0 = zf8 + (size_t)(rowBase + r0) * D_DIM + kb + gc0 * 16;
        const unsigned char* ga1 = zf8 + (size_t)(rowBase + r1) * D_DIM + kb + gc1 * 16;
        const unsigned char* gb0 = zf8 + (size_t)(colBase + r0) * D_DIM + kb + gc0 * 16;
        const unsigned char* gb1 = zf8 + (size_t)(colBase + r1) * D_DIM + kb + gc1 * 16;
        __builtin_amdgcn_global_load_lds((const g_u32*)ga0, (l_u32*)&As[ci0 * 16], 16, 0, 0);
        __builtin_amdgcn_global_load_lds((const g_u32*)ga1, (l_u32*)&As[ci1 * 16], 16, 0, 0);
        __builtin_amdgcn_global_load_lds((const g_u32*)gb0, (l_u32*)&Bs[ci0 * 16], 16, 0, 0);
        __builtin_amdgcn_global_load_lds((const g_u32*)gb1, (l_u32*)&Bs[ci1 * 16], 16, 0, 0);
        __syncthreads();

        // fragment 8B piece for k-half h: raw chunk = h*2 + (q>>1),
        // stored chunk = raw ^ ((row>>1)&3), byte-in-chunk = (q&1)*8.
        long long af[2][4], bfr[2][4];
        #pragma unroll
        for (int h = 0; h < 2; h++) {
            #pragma unroll
            for (int i = 0; i < 4; i++) {
                const int ra = wr * 64 + i * 16 + l15;
                const int rb = wc * 64 + i * 16 + l15;
                const int ca = ((h * 2 + (q >> 1)) ^ ((ra >> 1) & 3)) * 16 + (q & 1) * 8;
                const int cb = ((h * 2 + (q >> 1)) ^ ((rb >> 1) & 3)) * 16 + (q & 1) * 8;
                af[h][i]  = *(const long long*)&As[ra * BK + ca];
                bfr[h][i] = *(const long long*)&Bs[rb * BK + cb];
            }
        }
        #pragma unroll
        for (int h = 0; h < 2; h++)
            #pragma unroll
            for (int i = 0; i < 4; i++)
                #pragma unroll
                for (int j = 0; j < 4; j++)
                    acc[i][j] = __builtin_amdgcn_mfma_f32_16x16x32_fp8_fp8(
                        af[h][i], bfr[h][j], acc[i][j], 0, 0, 0);
        __syncthreads();
    }

    // Epilogue. C/D layout (16x16 family): col = lane&15, row = (lane>>4)*4 + reg.
    float colacc[4] = {0.f, 0.f, 0.f, 0.f};
    #pragma unroll
    for (int i = 0; i < 4; i++) {
        #pragma unroll
        for (int r = 0; r < 4; r++) {
            const int row = rowBase + wr * 64 + i * 16 + q * 4 + r;
            float rs = 0.0f;
            #pragma unroll
            for (int j = 0; j < 4; j++) {
                const int col = colBase + wc * 64 + j * 16 + l15;
                const float c = acc[i][j][r];
                float e = __expf(c);
                if (isDiag && col == row) e = 0.0f;
                rs += e;
                colacc[j] += e;
                if (hasPos && col == row + HALF_N) { pos[row] = c; pos[col] = c; }
            }
            rs += __shfl_xor(rs, 1); rs += __shfl_xor(rs, 2);
            rs += __shfl_xor(rs, 4); rs += __shfl_xor(rs, 8);
            if (l15 == 0) atomicAdd(&rowsum[row], rs);
        }
    }
    if (!isDiag) {
        #pragma unroll
        for (int j = 0; j < 4; j++) {
            float cs = colacc[j];
            cs += __shfl_xor(cs, 16);
            cs += __shfl_xor(cs, 32);
            if (q == 0) atomicAdd(&rowsum[colBase + wc * 64 + j * 16 + l15], cs);
        }
    }
}

// Kernel 3: mean over rows of (log(rowsum) - pos) -> scalar (out pre-zeroed).
__global__ __launch_bounds__(256) void k_finalize(
    const float* __restrict__ rowsum, const float* __restrict__ pos,
    float* __restrict__ out)
{
    const int t = threadIdx.x;
    const int i = blockIdx.x * 256 + t;
    float s = logf(rowsum[i]) - pos[i];
    #pragma unroll
    for (int m = 1; m < 64; m <<= 1) s += __shfl_xor(s, m, 64);
    __shared__ float red[4];
    if ((t & 63) == 0) red[t >> 6] = s;
    __syncthreads();
    if (t == 0)
        atomicAdd(out, (red[0] + red[1] + red[2] + red[3]) * (1.0f / (float)N_TOT));
}

extern "C" void kernel_launch(void* const* d_in, const int* in_sizes, int n_in,
                              void* d_out, int out_size, void* d_ws, size_t ws_size,
                              hipStream_t stream) {
    const float* p1 = (const float*)d_in[0];
    const float* p2 = (const float*)d_in[1];

    unsigned char* zf8 = (unsigned char*)d_ws;                          // 4 MB
    float* rowsum = (float*)((char*)d_ws + (size_t)N_TOT * D_DIM);      // 32 KB
    float* pos    = rowsum + N_TOT;                                     // 32 KB
    float* outp   = (float*)d_out;

    k_normalize<<<N_TOT / 4, 256, 0, stream>>>(p1, p2, zf8, rowsum, outp);
    k_gemm<<<NTILES, 256, 0, stream>>>(zf8, rowsum, pos);
    k_finalize<<<N_TOT / 256, 256, 0, stream>>>(rowsum, pos, outp);
}

// Round 8
// 108.892 us; speedup vs baseline: 2.9546x; 1.0033x over previous
//
#include <hip/hip_runtime.h>
#include <hip/hip_bf16.h>
#include <math.h>

#define N_TOT 8192
#define HALF_N 4096
#define D_DIM 512
#define BM 128
#define BK 64          // fp8 bytes per K-chunk; 8 K-iterations, 64B LDS rows
#define NKIT (D_DIM / BK)
#define NTILES 2080    // 64*65/2 upper-triangle 128x128 tiles

typedef float f32x4_t __attribute__((ext_vector_type(4)));

typedef __attribute__((address_space(1))) unsigned int g_u32;
typedef __attribute__((address_space(3))) unsigned int l_u32;

// Kernel 1: L2-normalize rows of [p1;p2] -> fp8 e4m3 Z; zero rowsum + out.
__global__ __launch_bounds__(256) void k_normalize(
    const float* __restrict__ p1, const float* __restrict__ p2,
    unsigned char* __restrict__ zf8, float* __restrict__ rowsum,
    float* __restrict__ out)
{
    const int w = threadIdx.x >> 6;
    const int lane = threadIdx.x & 63;
    const int row = blockIdx.x * 4 + w;

    if (threadIdx.x < 4) rowsum[blockIdx.x * 4 + threadIdx.x] = 0.0f;
    if (blockIdx.x == 0 && threadIdx.x == 0) out[0] = 0.0f;

    const float* src = (row < HALF_N) ? p1 + (size_t)row * D_DIM
                                      : p2 + (size_t)(row - HALF_N) * D_DIM;
    float4 a = *(const float4*)(src + lane * 4);
    float4 b = *(const float4*)(src + 256 + lane * 4);
    float s = a.x*a.x + a.y*a.y + a.z*a.z + a.w*a.w
            + b.x*b.x + b.y*b.y + b.z*b.z + b.w*b.w;
    #pragma unroll
    for (int m = 1; m < 64; m <<= 1) s += __shfl_xor(s, m, 64);
    float inv = 1.0f / fmaxf(sqrtf(s), 1e-8f);

    int pk0 = __builtin_amdgcn_cvt_pk_fp8_f32(a.x * inv, a.y * inv, 0, false);
    pk0     = __builtin_amdgcn_cvt_pk_fp8_f32(a.z * inv, a.w * inv, pk0, true);
    int pk1 = __builtin_amdgcn_cvt_pk_fp8_f32(b.x * inv, b.y * inv, 0, false);
    pk1     = __builtin_amdgcn_cvt_pk_fp8_f32(b.z * inv, b.w * inv, pk1, true);

    unsigned char* dst = zf8 + (size_t)row * D_DIM;
    *(int*)(dst + lane * 4) = pk0;
    *(int*)(dst + 256 + lane * 4) = pk1;
}

// Kernel 2: upper-triangle tiles of sim = Z*Z^T via fp8 MFMA 16x16x32.
// Double-buffered LDS: loads for iter k+1 are issued right after iter k's
// barrier, so each barrier's vmcnt(0) drain covers loads issued one full
// iteration earlier (latency hidden behind ds_read+MFMA). One barrier/iter.
// No __threadfence anywhere (R5/R6 regression: device fence => L2 inval).
__global__ __launch_bounds__(256, 3) void k_gemm(
    const unsigned char* __restrict__ zf8,
    float* __restrict__ rowsum, float* __restrict__ pos)
{
    __shared__ __align__(16) unsigned char As[2][BM * BK];  // 2 x 8 KB
    __shared__ __align__(16) unsigned char Bs[2][BM * BK];  // 2 x 8 KB

    const int tid = threadIdx.x;
    const int lane = tid & 63;
    const int w = tid >> 6;
    const int wr = w >> 1, wc = w & 1;
    const int q = lane >> 4, l15 = lane & 15;

    // triangular block mapping: t -> (bx >= by)
    const int t = blockIdx.x;
    int bi = (int)((sqrtf(8.0f * (float)t + 1.0f) - 1.0f) * 0.5f);
    while ((bi + 1) * (bi + 2) / 2 <= t) ++bi;
    while (bi * (bi + 1) / 2 > t) --bi;
    const int bx = bi;                       // col tile (larger)
    const int by = t - bi * (bi + 1) / 2;    // row tile
    const bool isDiag = (bx == by);
    const bool hasPos = (bx - by == 32);
    const int rowBase = by * BM;
    const int colBase = bx * BM;

    // staging geometry: 16B chunks; dest chunk index = tid and 256+tid
    // (lane-contiguous, required by global_load_lds). 64B rows -> row=ci>>2.
    const int ci0 = tid;
    const int ci1 = 256 + tid;
    const int r0 = ci0 >> 2, cc0 = ci0 & 3;
    const int r1 = ci1 >> 2, cc1 = ci1 & 3;
    const int gc0 = cc0 ^ ((r0 >> 1) & 3);   // XOR source swizzle
    const int gc1 = cc1 ^ ((r1 >> 1) & 3);

    const unsigned char* gA0 = zf8 + (size_t)(rowBase + r0) * D_DIM + gc0 * 16;
    const unsigned char* gA1 = zf8 + (size_t)(rowBase + r1) * D_DIM + gc1 * 16;
    const unsigned char* gB0 = zf8 + (size_t)(colBase + r0) * D_DIM + gc0 * 16;
    const unsigned char* gB1 = zf8 + (size_t)(colBase + r1) * D_DIM + gc1 * 16;

    f32x4_t acc[4][4] = {};

    // preload iter 0 into buffer 0
    __builtin_amdgcn_global_load_lds((const g_u32*)gA0, (l_u32*)&As[0][ci0 * 16], 16, 0, 0);
    __builtin_amdgcn_global_load_lds((const g_u32*)gA1, (l_u32*)&As[0][ci1 * 16], 16, 0, 0);
    __builtin_amdgcn_global_load_lds((const g_u32*)gB0, (l_u32*)&Bs[0][ci0 * 16], 16, 0, 0);
    __builtin_amdgcn_global_load_lds((const g_u32*)gB1, (l_u32*)&Bs[0][ci1 * 16], 16, 0, 0);

    #pragma unroll
    for (int it = 0; it < NKIT; it++) {
        const int cur = it & 1;
        __syncthreads();  // drains vmcnt -> buf[cur] ready; buf[1-cur] free

        if (it + 1 < NKIT) {
            const int kb = (it + 1) * BK;
            const int nxt = 1 - cur;
            __builtin_amdgcn_global_load_lds((const g_u32*)(gA0 + kb), (l_u32*)&As[nxt][ci0 * 16], 16, 0, 0);
            __builtin_amdgcn_global_load_lds((const g_u32*)(gA1 + kb), (l_u32*)&As[nxt][ci1 * 16], 16, 0, 0);
            __builtin_amdgcn_global_load_lds((const g_u32*)(gB0 + kb), (l_u32*)&Bs[nxt][ci0 * 16], 16, 0, 0);
            __builtin_amdgcn_global_load_lds((const g_u32*)(gB1 + kb), (l_u32*)&Bs[nxt][ci1 * 16], 16, 0, 0);
        }

        // fragment 8B piece for k-half h: raw chunk = h*2 + (q>>1),
        // stored chunk = raw ^ ((row>>1)&3), byte-in-chunk = (q&1)*8.
        long long af[2][4], bfr[2][4];
        #pragma unroll
        for (int h = 0; h < 2; h++) {
            #pragma unroll
            for (int i = 0; i < 4; i++) {
                const int ra = wr * 64 + i * 16 + l15;
                const int rb = wc * 64 + i * 16 + l15;
                const int ca = ((h * 2 + (q >> 1)) ^ ((ra >> 1) & 3)) * 16 + (q & 1) * 8;
                const int cb = ((h * 2 + (q >> 1)) ^ ((rb >> 1) & 3)) * 16 + (q & 1) * 8;
                af[h][i]  = *(const long long*)&As[cur][ra * BK + ca];
                bfr[h][i] = *(const long long*)&Bs[cur][rb * BK + cb];
            }
        }
        #pragma unroll
        for (int h = 0; h < 2; h++)
            #pragma unroll
            for (int i = 0; i < 4; i++)
                #pragma unroll
                for (int j = 0; j < 4; j++)
                    acc[i][j] = __builtin_amdgcn_mfma_f32_16x16x32_fp8_fp8(
                        af[h][i], bfr[h][j], acc[i][j], 0, 0, 0);
    }

    // Epilogue. C/D layout (16x16 family): col = lane&15, row = (lane>>4)*4 + reg.
    float colacc[4] = {0.f, 0.f, 0.f, 0.f};
    #pragma unroll
    for (int i = 0; i < 4; i++) {
        #pragma unroll
        for (int r = 0; r < 4; r++) {
            const int row = rowBase + wr * 64 + i * 16 + q * 4 + r;
            float rs = 0.0f;
            #pragma unroll
            for (int j = 0; j < 4; j++) {
                const int col = colBase + wc * 64 + j * 16 + l15;
                const float c = acc[i][j][r];
                float e = __expf(c);
                if (isDiag && col == row) e = 0.0f;
                rs += e;
                colacc[j] += e;
                if (hasPos && col == row + HALF_N) { pos[row] = c; pos[col] = c; }
            }
            rs += __shfl_xor(rs, 1); rs += __shfl_xor(rs, 2);
            rs += __shfl_xor(rs, 4); rs += __shfl_xor(rs, 8);
            if (l15 == 0) atomicAdd(&rowsum[row], rs);
        }
    }
    if (!isDiag) {
        #pragma unroll
        for (int j = 0; j < 4; j++) {
            float cs = colacc[j];
            cs += __shfl_xor(cs, 16);
            cs += __shfl_xor(cs, 32);
            if (q == 0) atomicAdd(&rowsum[colBase + wc * 64 + j * 16 + l15], cs);
        }
    }
}

// Kernel 3: mean over rows of (log(rowsum) - pos) -> scalar (out pre-zeroed).
__global__ __launch_bounds__(256) void k_finalize(
    const float* __restrict__ rowsum, const float* __restrict__ pos,
    float* __restrict__ out)
{
    const int t = threadIdx.x;
    const int i = blockIdx.x * 256 + t;
    float s = logf(rowsum[i]) - pos[i];
    #pragma unroll
    for (int m = 1; m < 64; m <<= 1) s += __shfl_xor(s, m, 64);
    __shared__ float red[4];
    if ((t & 63) == 0) red[t >> 6] = s;
    __syncthreads();
    if (t == 0)
        atomicAdd(out, (red[0] + red[1] + red[2] + red[3]) * (1.0f / (float)N_TOT));
}

extern "C" void kernel_launch(void* const* d_in, const int* in_sizes, int n_in,
                              void* d_out, int out_size, void* d_ws, size_t ws_size,
                              hipStream_t stream) {
    const float* p1 = (const float*)d_in[0];
    const float* p2 = (const float*)d_in[1];

    unsigned char* zf8 = (unsigned char*)d_ws;                          // 4 MB
    float* rowsum = (float*)((char*)d_ws + (size_t)N_TOT * D_DIM);      // 32 KB
    float* pos    = rowsum + N_TOT;                                     // 32 KB
    float* outp   = (float*)d_out;

    k_normalize<<<N_TOT / 4, 256, 0, stream>>>(p1, p2, zf8, rowsum, outp);
    k_gemm<<<NTILES, 256, 0, stream>>>(zf8, rowsum, pos);
    k_finalize<<<N_TOT / 256, 256, 0, stream>>>(rowsum, pos, outp);
}